// Round 8
// baseline (1932.457 us; speedup 1.0000x reference)
//
#include <hip/hip_runtime.h>
#include <stdint.h>

#define NND 50000
#define NNDP 50016            // table row-stride (sentinel zero row at index NND)
#define NE  1600000
#define INC 129
#define TP  25
#define NTR 25000
#define MPAD 50048
#define NC 192
#define NB_SCAN 196           // ceil(50000/256)
#define CSR_MAX (NE + 8*NND + 128)

typedef short bf16x8 __attribute__((ext_vector_type(8)));
typedef float f32x4 __attribute__((ext_vector_type(4)));
typedef float f32x2 __attribute__((ext_vector_type(2)));

__device__ __forceinline__ uint32_t f2bf(float f){
  union{float ff; uint32_t u;} v; v.ff=f;
  return (v.u + 0x7FFFu + ((v.u>>16)&1u))>>16;
}
__device__ __forceinline__ uint32_t pack2(float a, float b){
  return f2bf(a) | (f2bf(b)<<16);
}
__device__ __forceinline__ float sigm(float v){ return 1.f/(1.f+__expf(-v)); }

// -------- weight prep: Weff = W_g @ Wl_g[:64], FRAGMENT-MAJOR output --------
// BTf: 84 fragments (g,kk,cc), each 256 dwords: pos = frag*256 + lane*4 + dw,
// lane = kgrp*16 + col16; element (j = g*64+cc*16+col16, k: kd = kk*16+kgrp*4+dw).
__global__ void k_prep(const float* Wz, const float* bz, const float* Wlz, const float* blz,
                       const float* Wr, const float* br, const float* Wlr, const float* blr,
                       const float* Wh, const float* bh, const float* Wlh, const float* blh,
                       uint16_t* BTf, float* ceff, uint16_t* Wlf)
{
  int idx = blockIdx.x*256 + threadIdx.x;
  if (idx < NC*224) {
    int j = idx / 224, k = idx - j*224;
    int g = j >> 6, jj = j & 63;
    const float* W  = g==0?Wz :(g==1?Wr :Wh);
    const float* Wl = g==0?Wlz:(g==1?Wlr:Wlh);
    float v = 0.f;
    if (k < INC) {
      for (int m=0;m<64;m++) v += W[k*64+m]*Wl[m*64+jj];
    } else if (k >= 160) {
      int kk = k-160;
      v = (g<2) ? Wl[(64+kk)*64 + jj] : 0.f;
    }
    int cc = (j>>4)&3, c16 = j&15;
    int kd = k>>1, kk = kd>>4, kgrp = (kd>>2)&3, dw = kd&3, half = k&1;
    int lane = kgrp*16 + c16;
    BTf[(((g*7+kk)*4+cc)*256 + lane*4 + dw)*2 + half] = (uint16_t)f2bf(v);
  } else if (idx < NC*224 + 64*64) {
    int t = idx - NC*224; int j2 = t>>6, k2 = t&63;   // element WlhT[j2][k2] = Wl_h[64+k2][j2]
    int cc = j2>>4, c16 = j2&15;
    int kd = k2>>1, kk2 = kd>>4, kgrp = (kd>>2)&3, dw = kd&3, half = k2&1;
    int lane = kgrp*16 + c16;
    Wlf[((kk2*4+cc)*256 + lane*4 + dw)*2 + half] = (uint16_t)f2bf(Wlh[(64+k2)*64 + j2]);
  } else if (idx < NC*224 + 64*64 + NC) {
    int j = idx - NC*224 - 64*64;
    int g = j>>6, jj = j&63;
    const float* b  = g==0?bz :(g==1?br :bh);
    const float* Wl = g==0?Wlz:(g==1?Wlr:Wlh);
    const float* bl = g==0?blz:(g==1?blr:blh);
    float v = bl[jj];
    for (int m=0;m<64;m++) v += b[m]*Wl[m*64+jj];
    ceff[j] = v;
  }
}

__global__ void k_probs(const float* att, float* probs){
  if (threadIdx.x==0 && blockIdx.x==0){
    float m=-1e30f;
    for (int i=0;i<TP;i++) m = fmaxf(m, att[i]);
    float e[TP]; float s=0.f;
    for (int i=0;i<TP;i++){ e[i]=__expf(att[i]-m); s+=e[i]; }
    for (int i=0;i<TP;i++) probs[i]=e[i]/s;
  }
}

__global__ void k_hist(const int* eidx, int* deg){
  int e = blockIdx.x*256 + threadIdx.x;
  if (e < NE) atomicAdd(&deg[eidx[NE + e]], 1);   // dst row
}

__global__ void k_dinv(const int* deg, float* dinv){
  int n = blockIdx.x*256 + threadIdx.x;
  if (n < NND) dinv[n] = rsqrtf(1.0f + (float)deg[n]);
}

// ---- scan of padded row sizes p_i = (deg_i+1 rounded up to mult of 8) ----
__global__ void k_scan1(const int* deg, int* row_ptr, int* bsum){
  __shared__ int s[256];
  int tid = threadIdx.x;
  int i = blockIdx.x*256 + tid;
  int v = (i < NND) ? ((deg[i]+8)&~7) : 0;
  s[tid] = v; __syncthreads();
  for (int d=1; d<256; d<<=1){
    int t = (tid>=d) ? s[tid-d] : 0;
    __syncthreads();
    s[tid] += t; __syncthreads();
  }
  if (i < NND) row_ptr[i] = s[tid] - v;
  if (tid == 255) bsum[blockIdx.x] = s[255];
}
__global__ void k_scan2(int* bsum, int* boff, int* row_ptr){
  __shared__ int s[256];
  int tid = threadIdx.x;
  int v = (tid < NB_SCAN) ? bsum[tid] : 0;
  s[tid] = v; __syncthreads();
  for (int d=1; d<256; d<<=1){
    int t = (tid>=d) ? s[tid-d] : 0;
    __syncthreads();
    s[tid] += t; __syncthreads();
  }
  if (tid < NB_SCAN) boff[tid] = s[tid] - v;
  if (tid == NB_SCAN-1) row_ptr[NND] = s[tid];
}
__global__ void k_scan3(int* row_ptr, const int* boff){
  int i = blockIdx.x*256 + threadIdx.x;
  if (i < NND) row_ptr[i] += boff[blockIdx.x];
}

__global__ void k_fill(const int* eidx, const int* rp, int* cnt, uint16_t* csr){
  int e = blockIdx.x*256 + threadIdx.x;
  if (e < NE){
    int s = eidx[e], d = eidx[NE+e];
    int pos = rp[d] + atomicAdd(&cnt[d],1);
    csr[pos] = (uint16_t)s;
  }
}
// self-loop entry + sentinel padding (src=NND -> zero table row)
__global__ void k_self(const int* rp, const int* deg, uint16_t* csr){
  int n = blockIdx.x*256 + threadIdx.x;
  if (n < NND){
    int base = rp[n] + deg[n];
    int endp = rp[n+1];
    csr[base] = (uint16_t)n;
    for (int j=base+1; j<endp; j++) csr[j] = (uint16_t)NND;
  }
}

// x (N,129,25) fp32 -> tables pre-scaled by dinv[n]:
//   xT8[t][n][32 uints]  (ch 0..127 as fp8 e4m3, 128B rows = 1 cache line)
//   xsl[t][n] f32        (ch 128, exact)
__global__ __launch_bounds__(256) void k_transpose3(const float* __restrict__ x,
                                                    const float* __restrict__ dinv,
                                                    uint32_t* __restrict__ xT8,
                                                    float* __restrict__ xsl){
  __shared__ float lx[3232];           // 129*25 = 3225
  int n = blockIdx.x;
  const float* xr = x + (size_t)n*(INC*TP);
  for (int e=threadIdx.x; e<INC*TP; e+=256) lx[e] = xr[e];
  __syncthreads();
  float dv = dinv[n];
  for (int idx=threadIdx.x; idx<TP*32; idx+=256){
    int t = idx>>5, u = idx&31;
    int c0 = u*4;
    float v0 = lx[(c0+0)*TP+t]*dv, v1 = lx[(c0+1)*TP+t]*dv;
    float v2 = lx[(c0+2)*TP+t]*dv, v3 = lx[(c0+3)*TP+t]*dv;
    int wlo = __builtin_amdgcn_cvt_pk_fp8_f32(v0, v1, 0, false);
    int w   = __builtin_amdgcn_cvt_pk_fp8_f32(v2, v3, wlo, true);
    xT8[((size_t)t*NNDP + n)*32 + u] = (uint32_t)w;
  }
  for (int t=threadIdx.x; t<TP; t+=256)
    xsl[(size_t)t*NNDP + n] = dv*lx[128*TP + t];
  if (blockIdx.x == 0){                // zero the sentinel rows
    for (int idx=threadIdx.x; idx<TP*32; idx+=256){
      int t = idx>>5, u = idx&31;
      xT8[((size_t)t*NNDP + NND)*32 + u] = 0u;
    }
    for (int t=threadIdx.x; t<TP; t+=256) xsl[(size_t)t*NNDP + NND] = 0.f;
  }
}

// Aggregation, scheme D + fp8: wave per (dst,t); edges serial; per edge ONE
// wave-uniform coalesced 128B row load, scalar CSR via s_load, HW fp8 decode.
__global__ __launch_bounds__(256) void k_agg(const uint16_t* __restrict__ xT8,
    const int* __restrict__ rp, const uint16_t* __restrict__ csr,
    const float* __restrict__ dinv, uint32_t* __restrict__ AX)
{
  int t = blockIdx.y;
  int wave = threadIdx.x>>6, lane = threadIdx.x&63;
  int d = blockIdx.x*4 + wave;
  int beg = __builtin_amdgcn_readfirstlane(rp[d]);
  int end = __builtin_amdgcn_readfirstlane(rp[d+1]);
  const uint16_t* tbl = xT8 + (size_t)t*((size_t)NNDP*64);   // 64 ushorts/row
  float a0=0.f, a1=0.f;
  for (int i0=beg; i0<end; i0+=8){
    ulonglong2 c = *(const ulonglong2*)(csr + i0);   // uniform -> s_load
    #pragma unroll
    for (int k=0;k<4;k++){
      int s0 = (int)((c.x >> (k*16)) & 0xFFFFu);     // scalar extracts
      int s1 = (int)((c.y >> (k*16)) & 0xFFFFu);
      uint32_t u0 = tbl[(size_t)s0*64 + lane];       // 128B row, 1 line
      uint32_t u1 = tbl[(size_t)s1*64 + lane];
      f32x2 v0 = __builtin_amdgcn_cvt_pk_f32_fp8((int)u0, false);
      f32x2 v1 = __builtin_amdgcn_cvt_pk_f32_fp8((int)u1, false);
      a0 += v0.x; a1 += v0.y;
      a0 += v1.x; a1 += v1.y;
    }
  }
  float dv = dinv[d];
  AX[(size_t)t*((size_t)MPAD*80) + (size_t)d*80 + lane] = pack2(dv*a0, dv*a1);
}

// channel 128: thread per (dst,t), gathers from L2-resident 200KB f32 plane
__global__ void k_aggL(const float* __restrict__ xsl,
    const int* __restrict__ rp, const uint16_t* __restrict__ csr,
    const float* __restrict__ dinv, uint32_t* __restrict__ AX)
{
  int t = blockIdx.y;
  int d = blockIdx.x*256 + threadIdx.x;
  if (d >= NND) return;
  const float* pl = xsl + (size_t)t*NNDP;
  float a = 0.f;
  int beg=rp[d], end=rp[d+1];
  #pragma unroll 4
  for (int i=beg;i<end;i++) a += pl[(int)csr[i]];
  AX[(size_t)t*((size_t)MPAD*80) + (size_t)d*80 + 64] = pack2(dinv[d]*a, 0.f);
}

// Fused full recurrence, barrier-free: each WAVE owns 16 nodes for ALL 25 steps.
// A-fragments (AX) load global->regs; B-fragments (BTf/Wlf) load global (L2-hot,
// fragment-major, lane-linear); only H and HR transit LDS (fragment-major,
// conflict-free lane*16 reads). No __syncthreads anywhere.
__global__ __launch_bounds__(256) void k_gru(const uint32_t* __restrict__ AX,
    const uint32_t* __restrict__ BTf, const float* __restrict__ ceff,
    const uint32_t* __restrict__ Wlf, float* __restrict__ accum,
    const float* __restrict__ probs)
{
  __shared__ __align__(16) uint32_t lds4[4*1024];  // per wave: H[2][256], HR[2][256]
  int tid = threadIdx.x;
  int wave = tid>>6, lane = tid&63;
  int col16 = lane&15, kgrp = lane>>4;
  uint32_t* myH  = &lds4[wave*1024];
  uint32_t* myHR = &lds4[wave*1024 + 512];
  int n0 = blockIdx.x*64;

  // H fragments start at zero (H0 = 0)
  for (int p=lane; p<512; p+=64) myH[p] = 0u;

  // ceff cached in registers
  float cz[4], cr[4], ch[4];
  #pragma unroll
  for (int cc=0;cc<4;cc++){
    cz[cc] = ceff[cc*16+col16];
    cr[cc] = ceff[64+cc*16+col16];
    ch[cc] = ceff[128+cc*16+col16];
  }

  f32x4 h[4] = {{0,0,0,0},{0,0,0,0},{0,0,0,0},{0,0,0,0}};
  f32x4 acr[4] = {{0,0,0,0},{0,0,0,0},{0,0,0,0},{0,0,0,0}};

  for (int t=0; t<TP; t++){
    // A-fragments: X part direct from global (5 coalesced b128/lane)
    const uint32_t* AXrow = AX + (size_t)t*((size_t)MPAD*80)
                               + (size_t)(n0 + wave*16 + col16)*80 + kgrp*4;
    bf16x8 ax[5];
    #pragma unroll
    for (int kk=0; kk<5; kk++) ax[kk] = *(const bf16x8*)(AXrow + kk*16);
    // H part from LDS (written by this wave last step)
    bf16x8 hf0 = *(const bf16x8*)&myH[lane*4];
    bf16x8 hf1 = *(const bf16x8*)&myH[256 + lane*4];

    // GEMM1: fragment-major B direct from global (L2-resident)
    f32x4 accg[3][4] = {};
    #pragma unroll
    for (int g=0; g<3; g++){
      #pragma unroll
      for (int kk=0; kk<7; kk++){
        bf16x8 a = (kk<5) ? ax[kk] : ((kk==5) ? hf0 : hf1);
        #pragma unroll
        for (int cc=0; cc<4; cc++){
          bf16x8 b = *(const bf16x8*)(BTf + (((g*7+kk)*4+cc)<<8) + lane*4);
          accg[g][cc] = __builtin_amdgcn_mfma_f32_16x16x32_bf16(a,b,accg[g][cc],0,0,0);
        }
      }
    }

    // epilogue A: gates; HR -> LDS fragment-major (pair lanes via shfl)
    #pragma unroll
    for (int cc=0;cc<4;cc++){
      #pragma unroll
      for (int j=0;j<4;j++){
        float z  = sigm(accg[0][cc][j] + cz[cc]);
        float r  = sigm(accg[1][cc][j] + cr[cc]);
        float ph = accg[2][cc][j] + ch[cc];
        accg[0][cc][j] = z;
        accg[2][cc][j] = ph;
        float hr = h[cc][j]*r;
        float prt = __shfl_xor(hr, 1);
        if (!(col16 & 1)){
          int q = cc*8 + (col16>>1);
          myHR[((q>>4)<<8) + ((((q>>2)&3)*16 + kgrp*4 + j)<<2) + (q&3)] = pack2(hr, prt);
        }
      }
    }

    // GEMM2: HR @ WlhT (fragment-major, lane-linear reads)
    f32x4 acc2[4] = {};
    #pragma unroll
    for (int kk2=0; kk2<2; kk2++){
      bf16x8 a2 = *(const bf16x8*)&myHR[(kk2<<8) + lane*4];
      #pragma unroll
      for (int cc=0; cc<4; cc++){
        bf16x8 b2 = *(const bf16x8*)(Wlf + (((kk2*4+cc))<<8) + lane*4);
        acc2[cc] = __builtin_amdgcn_mfma_f32_16x16x32_bf16(a2,b2,acc2[cc],0,0,0);
      }
    }

    // epilogue B: GRU update; H(f32) regs; H(bf16) -> LDS frags; accum regs
    float pt = probs[t];
    #pragma unroll
    for (int cc=0;cc<4;cc++){
      #pragma unroll
      for (int j=0;j<4;j++){
        float ht = tanhf(acc2[cc][j] + accg[2][cc][j]);
        float z = accg[0][cc][j];
        float hn = z*h[cc][j] + (1.f-z)*ht;
        h[cc][j] = hn;
        acr[cc][j] += pt*hn;
        float prt = __shfl_xor(hn, 1);
        if (!(col16 & 1)){
          int q = cc*8 + (col16>>1);
          myH[((q>>4)<<8) + ((((q>>2)&3)*16 + kgrp*4 + j)<<2) + (q&3)] = pack2(hn, prt);
        }
      }
    }
  }

  // write attention accumulator once
  #pragma unroll
  for (int cc=0;cc<4;cc++){
    #pragma unroll
    for (int j=0;j<4;j++){
      int n = n0 + wave*16 + kgrp*4 + j;
      if (n < NND)
        accum[(size_t)n*64 + cc*16 + col16] = acr[cc][j];
    }
  }
}

__global__ void k_out(const int* train_idx, const float* accum, const float* Wo,
                      const float* bo, const float* y, float* out){
  int i = blockIdx.x*256 + threadIdx.x;
  if (i < NTR){
    int n = train_idx[i];
    float s = bo[0];
    const float* ar = accum + (size_t)n*64;
    #pragma unroll
    for (int j=0;j<64;j++) s += ar[j]*Wo[j];
    out[i] = sigm(s);
    out[NTR+i] = y[n];
  }
}

extern "C" void kernel_launch(void* const* d_in, const int* in_sizes, int n_in,
                              void* d_out, int out_size, void* d_ws, size_t ws_size,
                              hipStream_t stream)
{
  const float* x   = (const float*)d_in[0];
  const int*   eix = (const int*)d_in[1];
  const float* y   = (const float*)d_in[2];
  const int*   tri = (const int*)d_in[3];
  const float* Wz  = (const float*)d_in[4];
  const float* bz  = (const float*)d_in[5];
  const float* Wlz = (const float*)d_in[6];
  const float* blz = (const float*)d_in[7];
  const float* Wr  = (const float*)d_in[8];
  const float* br  = (const float*)d_in[9];
  const float* Wlr = (const float*)d_in[10];
  const float* blr = (const float*)d_in[11];
  const float* Wh  = (const float*)d_in[12];
  const float* bh  = (const float*)d_in[13];
  const float* Wlh = (const float*)d_in[14];
  const float* blh = (const float*)d_in[15];
  const float* att = (const float*)d_in[16];
  const float* Wo  = (const float*)d_in[17];
  const float* bo  = (const float*)d_in[18];
  float* out = (float*)d_out;

  char* w = (char*)d_ws;
  size_t off = 0;
  auto alloc = [&](size_t sz)->size_t{ size_t o=off; off=(off+sz+255)&~(size_t)255; return o; };

  // --- zero block (one small memset) ---
  size_t zo = off;
  size_t o_deg   = alloc((size_t)NND*4);
  size_t o_cnt   = alloc((size_t)NND*4);
  size_t zlen = off - zo;
  // --- rest ---
  size_t o_dinv  = alloc((size_t)NND*4);
  size_t o_rp    = alloc((size_t)(NND+1)*4);
  size_t o_bsum  = alloc((size_t)NB_SCAN*4);
  size_t o_boff  = alloc((size_t)NB_SCAN*4);
  size_t o_csr   = alloc((size_t)CSR_MAX*2);
  size_t o_BT    = alloc((size_t)NC*224*2);
  size_t o_ceff  = alloc((size_t)NC*4);
  size_t o_Wlf   = alloc((size_t)64*64*2);
  size_t o_probs = alloc((size_t)TP*4);
  size_t o_accum = alloc((size_t)MPAD*64*4);
  size_t o_AX    = alloc((size_t)TP*MPAD*80*4);   // 400 MB, all t
  size_t o_xT8   = alloc((size_t)TP*NNDP*128);    // 160 MB (fp8 table)
  size_t o_xl    = alloc((size_t)TP*NNDP*4);      // 5 MB
  (void)ws_size; (void)in_sizes; (void)n_in; (void)out_size;

  int*      deg   = (int*)(w+o_deg);
  int*      cnt   = (int*)(w+o_cnt);
  float*    dinv  = (float*)(w+o_dinv);
  int*      rp    = (int*)(w+o_rp);
  int*      bsum  = (int*)(w+o_bsum);
  int*      boff  = (int*)(w+o_boff);
  uint16_t* csr   = (uint16_t*)(w+o_csr);
  uint16_t* BTf   = (uint16_t*)(w+o_BT);
  float*    ceff  = (float*)(w+o_ceff);
  uint16_t* Wlf   = (uint16_t*)(w+o_Wlf);
  float*    probs = (float*)(w+o_probs);
  float*    accum = (float*)(w+o_accum);
  uint32_t* AX    = (uint32_t*)(w+o_AX);
  uint32_t* xT8   = (uint32_t*)(w+o_xT8);
  float*    xsl   = (float*)(w+o_xl);

  hipMemsetAsync(w+zo, 0, zlen, stream);

  k_prep<<<(NC*224 + 64*64 + NC + 255)/256, 256, 0, stream>>>(
      Wz,bz,Wlz,blz, Wr,br,Wlr,blr, Wh,bh,Wlh,blh, BTf, ceff, Wlf);
  k_probs<<<1, 64, 0, stream>>>(att, probs);
  k_hist<<<(NE+255)/256, 256, 0, stream>>>(eix, deg);
  k_dinv<<<(NND+255)/256, 256, 0, stream>>>(deg, dinv);
  k_scan1<<<NB_SCAN, 256, 0, stream>>>(deg, rp, bsum);
  k_scan2<<<1, 256, 0, stream>>>(bsum, boff, rp);
  k_scan3<<<NB_SCAN, 256, 0, stream>>>(rp, boff);
  k_fill<<<(NE+255)/256, 256, 0, stream>>>(eix, rp, cnt, csr);
  k_self<<<NB_SCAN, 256, 0, stream>>>(rp, deg, csr);
  k_transpose3<<<NND, 256, 0, stream>>>(x, dinv, xT8, xsl);

  k_agg <<<dim3(12500, TP), 256, 0, stream>>>((const uint16_t*)xT8, rp, csr, dinv, AX);
  k_aggL<<<dim3(NB_SCAN, TP), 256, 0, stream>>>(xsl, rp, csr, dinv, AX);

  k_gru<<<MPAD/64, 256, 0, stream>>>(AX, (const uint32_t*)BTf, ceff,
                                     (const uint32_t*)Wlf, accum, probs);
  k_out<<<(NTR+255)/256, 256, 0, stream>>>(tri, accum, Wo, bo, y, out);
}